// Round 16
// baseline (229.133 us; speedup 1.0000x reference)
//
#include <hip/hip_runtime.h>

#define N_PIX 50176
#define W_IMG 224
#define ROWS 32
#define NBX 24           // blocks per image: 3 blocks/CU; tiles contiguous

typedef __attribute__((ext_vector_type(8))) short s8v;   // 8 bf16
typedef __attribute__((ext_vector_type(4))) float f4v;
typedef __attribute__((ext_vector_type(2))) __bf16 bf2v;

__device__ __forceinline__ unsigned short f2bf(float f) {
    __bf16 h = (__bf16)f;
    return __builtin_bit_cast(unsigned short, h);
}
// pack two f32 -> two bf16 (RNE) in one u32; compiler emits v_cvt_pk_bf16_f32
__device__ __forceinline__ unsigned int pack2bf(float lo, float hi) {
    bf2v v = {(__bf16)lo, (__bf16)hi};
    return __builtin_bit_cast(unsigned int, v);
}

// swizzles: 256B rows (bufA/bufB), 128B rows (bufC/emloc)
#define SWZ(r, cb)  (((r) << 8) + ((cb) ^ (((r) & 15) << 4)))
#define CSWZ(r, cb) (((r) << 7) + ((cb) ^ (((r) & 7) << 4)))

__device__ __forceinline__ void gld_lds16(const void* g, void* l) {
    __builtin_amdgcn_global_load_lds(
        (const __attribute__((address_space(1))) unsigned int*)g,
        (__attribute__((address_space(3))) unsigned int*)l, 16, 0, 0);
}

// ---------------------------------------------------------------------------
// K0: Wk[col][k] (bf16, [128][192]): k<128 -> (w_obs2 @ w_ol1_top)^T
//                                    k>=128 -> w_ol1_bot^T  (em_loc extension)
//     wol2t[o][k]  = w_ol2^T  (bf16, [64][128])
//     wloc2t[o][k] = w_loc2^T (bf16, [64][128])
//     bias_c[h2]   = b_ol1[h2] + b_obs2 @ w_ol1_top
// ---------------------------------------------------------------------------
__global__ void k0_weights(const float* __restrict__ w_obs2, const float* __restrict__ b_obs2,
                           const float* __restrict__ w_ol1, const float* __restrict__ b_ol1,
                           const float* __restrict__ w_ol2, const float* __restrict__ w_loc2,
                           unsigned short* __restrict__ Wk,
                           unsigned short* __restrict__ wol2t,
                           unsigned short* __restrict__ wloc2t,
                           float* __restrict__ bias_c) {
    int bid = blockIdx.x, t = threadIdx.x;
    if (bid < 64) {
        int lin = bid * 256 + t;
        int n = lin >> 7, k = lin & 127;
        float s = 0.f;
        #pragma unroll
        for (int e = 0; e < 64; ++e) s = fmaf(w_obs2[k * 64 + e], w_ol1[e * 128 + n], s);
        Wk[n * 192 + k] = f2bf(s);
    } else if (bid < 96) {
        int lin = (bid - 64) * 256 + t;
        int n = lin >> 6, k = lin & 63;
        Wk[n * 192 + 128 + k] = f2bf(w_ol1[(64 + k) * 128 + n]);
    } else if (bid < 128) {
        int lin = (bid - 96) * 256 + t;
        int n = lin >> 7, k = lin & 127;
        wol2t[n * 128 + k] = f2bf(w_ol2[k * 64 + n]);
    } else if (bid < 160) {
        int lin = (bid - 128) * 256 + t;
        int n = lin >> 7, k = lin & 127;
        wloc2t[n * 128 + k] = f2bf(w_loc2[k * 64 + n]);
    } else {
        if (t < 128) {
            float s = b_ol1[t];
            #pragma unroll
            for (int e = 0; e < 64; ++e) s = fmaf(b_obs2[e], w_ol1[e * 128 + t], s);
            bias_c[t] = s;
        }
    }
}

// ---------------------------------------------------------------------------
// K1: em_loc via MFMA -> emloc stored PRE-SWIZZLED: element(n,o) at
//     emloc[n*64 + (o ^ ((n&7)<<3))]  (so k2 can DMA it linearly into LDS
//     and read with the CSWZ involution).
// ---------------------------------------------------------------------------
__global__ __launch_bounds__(256) void k1_loc(
        const float* __restrict__ w_loc1, const float* __restrict__ b_loc1,
        const unsigned short* __restrict__ wloc2t, const float* __restrict__ b_loc2,
        unsigned short* __restrict__ emloc) {
    __shared__ char hbuf[64 * 256];
    typedef __attribute__((ext_vector_type(4))) unsigned int u4v;

    const int t = threadIdx.x;
    const int n0 = blockIdx.x * 64;
    const int row = t >> 2, h0 = (t & 3) * 32;
    {
        int n = n0 + row;
        int iy = n / W_IMG, ix = n % W_IMG;
        float y = -10.f + (20.f / 223.f) * (float)iy;
        float x = -10.f + (20.f / 223.f) * (float)ix;
        #pragma unroll
        for (int q4 = 0; q4 < 4; ++q4) {
            int hb = h0 + q4 * 8;
            u4v pk;
            #pragma unroll
            for (int jj = 0; jj < 2; ++jj) {
                f4v wy = *(const f4v*)(w_loc1 + hb + jj * 4);
                f4v wx = *(const f4v*)(w_loc1 + 128 + hb + jj * 4);
                f4v bb = *(const f4v*)(b_loc1 + hb + jj * 4);
                #pragma unroll
                for (int j2 = 0; j2 < 2; ++j2) {
                    float v0 = fmaxf(fmaf(y, wy[j2 * 2], fmaf(x, wx[j2 * 2], bb[j2 * 2])), 0.f);
                    float v1 = fmaxf(fmaf(y, wy[j2 * 2 + 1], fmaf(x, wx[j2 * 2 + 1], bb[j2 * 2 + 1])), 0.f);
                    pk[jj * 2 + j2] = pack2bf(v0, v1);
                }
            }
            *(u4v*)(hbuf + SWZ(row, hb * 2)) = pk;
        }
    }
    __syncthreads();
    {
        const int w = t >> 6, l = t & 63;
        const int l15 = l & 15, lg = l >> 4;
        s8v a[4];
        #pragma unroll
        for (int ks = 0; ks < 4; ++ks)
            a[ks] = *(const s8v*)(hbuf + SWZ(w * 16 + l15, ks * 64 + lg * 16));
        #pragma unroll
        for (int nt = 0; nt < 4; ++nt) {
            f4v acc = {0.f, 0.f, 0.f, 0.f};
            #pragma unroll
            for (int ks = 0; ks < 4; ++ks) {
                s8v bfr = *(const s8v*)(wloc2t + (nt * 16 + l15) * 128 + ks * 32 + lg * 8);
                acc = __builtin_amdgcn_mfma_f32_16x16x32_bf16(a[ks], bfr, acc, 0, 0, 0);
            }
            float bb = b_loc2[nt * 16 + l15];
            int o = nt * 16 + l15;
            #pragma unroll
            for (int r = 0; r < 4; ++r) {
                int n = n0 + w * 16 + lg * 4 + r;
                emloc[(size_t)n * 64 + (o ^ ((n & 7) << 3))] = f2bf(acc[r] + bb);
            }
        }
    }
}

// ---------------------------------------------------------------------------
// K2: 3-stage pipeline, 1 barrier/iter, DMA-prefetched inputs.
//   512 threads / 8 waves: (ms = w>>2) x (cq = w&3) — each wave does HALF
//   the R15 per-iter work (one pixel-half). Same 32-row tile, same LDS
//   (41984 -> 3 blocks/CU), lean body (76 VGPR) -> target 24 waves/CU
//   (75% occupancy) vs R15's 12 (27% measured). Grid 24 x 32 = 3 blocks/CU.
//   (512, 2) reg cap — never tighten (R5/R8 spill lessons).
//   S1 (MFMA): hidden_obs = relu([w_obs1|b_obs1] @ [x|1]) zero-padded K.
//   S3 (MFMA, swapped, bias-init acc): relu(Wk @ [actT; emlocT]) -> bufB.
//   S4 (MFMA, swapped, bias-init acc): softplus via exp2/log2+fma -> spacc.
// ---------------------------------------------------------------------------
__global__ __launch_bounds__(512, 2) void k2_main(
        const float* __restrict__ images,
        const float* __restrict__ w_obs1, const float* __restrict__ b_obs1,
        const unsigned short* __restrict__ Wk, const float* __restrict__ biasc,
        const unsigned short* __restrict__ wol2t, const float* __restrict__ b_ol2,
        const unsigned short* __restrict__ emloc,
        float* __restrict__ part)          // [32][24][64]
{
    __shared__ char bufA[2][ROWS * 256];
    __shared__ char bufB[2][ROWS * 256];
    __shared__ char bufC[2][ROWS * 128];
    __shared__ f4v bufI4[2][24];           // [ch][32] floats per buffer
    __shared__ float red[8][16];

    const int t = threadIdx.x;
    const int w = t >> 6, l = t & 63;
    const int l15 = l & 15, lg = l >> 4;
    const int cq = w & 3, ms = w >> 2;
    const int p = ms * 16 + l15;           // this wave's pixel row
    const int bx = blockIdx.x, b = blockIdx.y;
    const int start = bx * 65 + (bx < 8 ? bx : 8);
    const int cnt = 65 + (bx < 8 ? 1 : 0);
    const size_t imgb = (size_t)b * 3 * N_PIX;
    #define PBASE(k) ((start + (k)) * ROWS)

    // S1 A-fragments (persistent): [w_obs1 | b_obs1] for 2 h-tiles of 16.
    // k-slots 0..3 = {w[0][h], w[1][h], w[2][h], b[h]}; lanes lg>=1 hold ZERO.
    s8v a1[2];
    #pragma unroll
    for (int mt = 0; mt < 2; ++mt) {
        int hh = cq * 32 + mt * 16 + l15;
        unsigned int lo = pack2bf(w_obs1[hh], w_obs1[128 + hh]);
        unsigned int hi = pack2bf(w_obs1[256 + hh], b_obs1[hh]);
        if (lg != 0) { lo = 0u; hi = 0u; }
        typedef __attribute__((ext_vector_type(4))) unsigned int u4;
        u4 u = {lo, hi, 0u, 0u};
        a1[mt] = __builtin_bit_cast(s8v, u);
    }

    // GEMM1 A fragments (weights, persistent): 2 h2-tiles x 6 k-steps
    s8v bw[2][6];
    #pragma unroll
    for (int nt = 0; nt < 2; ++nt) {
        int col = cq * 32 + nt * 16 + l15;
        #pragma unroll
        for (int ks = 0; ks < 6; ++ks)
            bw[nt][ks] = *(const s8v*)(Wk + col * 192 + ks * 32 + lg * 8);
    }
    // GEMM2 A fragments
    s8v w2f[4];
    {
        int o = cq * 16 + l15;
        #pragma unroll
        for (int ks = 0; ks < 4; ++ks)
            w2f[ks] = *(const s8v*)(wol2t + o * 128 + ks * 32 + lg * 8);
    }
    // bias vectors double as MFMA C-in (D row depends only on lg,r)
    const f4v bias30 = *(const f4v*)(biasc + cq * 32 + lg * 4);
    const f4v bias31 = *(const f4v*)(biasc + cq * 32 + 16 + lg * 4);
    const f4v bias4  = *(const f4v*)(b_ol2 + cq * 16 + lg * 4);

    f4v spacc = {0.f, 0.f, 0.f, 0.f};

    // preload img tile 0 (wave 1, 24 lanes x 16B = 3 ch x 128B)
    if (w == 1 && l < 24) {
        const char* src = (const char*)(images + imgb + (l >> 3) * N_PIX + PBASE(0)) + (l & 7) * 16;
        gld_lds16(src, (char*)bufI4[0]);
    }
    __syncthreads();

    for (int i = 0; i <= cnt + 1; ++i) {
        const int par = i & 1;
        // ---- DMA: emloc tile i -> bufC[par] (waves 0-3, 16B each)
        if (i < cnt && w < 4) {
            const char* src = (const char*)emloc +
                (size_t)(PBASE(i) + w * 8 + (l >> 3)) * 128 + (l & 7) * 16;
            gld_lds16(src, (char*)bufC[par] + w * 1024);
        }
        // ---- DMA: img tile i+1 -> bufI[par^1] (wave 5, 24 lanes)
        if (i + 1 < cnt && w == 5 && l < 24) {
            const char* src = (const char*)(images + imgb + (l >> 3) * N_PIX +
                                            PBASE(i + 1)) + (l & 7) * 16;
            gld_lds16(src, (char*)bufI4[par ^ 1]);
        }
        // ---- S1 (MFMA): hidden_obs(tile i), this wave's pixel half
        if (i < cnt) {
            const float* bI = (const float*)bufI4[par];
            char* bA = bufA[par];
            float x0 = bI[p], x1 = bI[32 + p], x2 = bI[64 + p];
            typedef __attribute__((ext_vector_type(4))) unsigned int u4;
            u4 u = {pack2bf(x0, x1), pack2bf(x2, 1.0f), 0u, 0u};
            s8v bfr = __builtin_bit_cast(s8v, u);
            #pragma unroll
            for (int mt = 0; mt < 2; ++mt) {
                f4v acc = {0.f, 0.f, 0.f, 0.f};
                acc = __builtin_amdgcn_mfma_f32_16x16x32_bf16(a1[mt], bfr, acc, 0, 0, 0);
                f4v z = {0.f, 0.f, 0.f, 0.f};
                acc = __builtin_elementwise_max(acc, z);
                uint2 pk;
                pk.x = pack2bf(acc[0], acc[1]);
                pk.y = pack2bf(acc[2], acc[3]);
                // h = cq*32 + mt*16 + lg*4 + r, pixel = p
                *(uint2*)(bA + SWZ(p, cq * 64 + mt * 32 + lg * 8)) = pk;
            }
        }
        // ---- S3 (tile i-1): this wave's pixel half; acc-init = bias
        if (i >= 1 && i <= cnt) {
            const char* bA = bufA[par ^ 1];
            const char* bC = bufC[par ^ 1];
            char* bB = bufB[par ^ 1];
            s8v bf[4];
            #pragma unroll
            for (int ks = 0; ks < 4; ++ks)
                bf[ks] = *(const s8v*)(bA + SWZ(p, ks * 64 + lg * 16));
            s8v c0 = *(const s8v*)(bC + CSWZ(p, lg * 16));
            s8v c1 = *(const s8v*)(bC + CSWZ(p, lg * 16 + 64));
            f4v acc0 = bias30, acc1 = bias31;
            __builtin_amdgcn_s_setprio(1);
            #pragma unroll
            for (int ks = 0; ks < 4; ++ks) {
                acc0 = __builtin_amdgcn_mfma_f32_16x16x32_bf16(bw[0][ks], bf[ks], acc0, 0, 0, 0);
                acc1 = __builtin_amdgcn_mfma_f32_16x16x32_bf16(bw[1][ks], bf[ks], acc1, 0, 0, 0);
            }
            acc0 = __builtin_amdgcn_mfma_f32_16x16x32_bf16(bw[0][4], c0, acc0, 0, 0, 0);
            acc1 = __builtin_amdgcn_mfma_f32_16x16x32_bf16(bw[1][4], c0, acc1, 0, 0, 0);
            acc0 = __builtin_amdgcn_mfma_f32_16x16x32_bf16(bw[0][5], c1, acc0, 0, 0, 0);
            acc1 = __builtin_amdgcn_mfma_f32_16x16x32_bf16(bw[1][5], c1, acc1, 0, 0, 0);
            __builtin_amdgcn_s_setprio(0);
            // D[h2][pixel=p] -> bufB[p][h2], 4 consecutive h2 per acc
            f4v z = {0.f, 0.f, 0.f, 0.f};
            f4v v0 = __builtin_elementwise_max(acc0, z);
            f4v v1 = __builtin_elementwise_max(acc1, z);
            uint2 w0p, w1p;
            w0p.x = pack2bf(v0[0], v0[1]);
            w0p.y = pack2bf(v0[2], v0[3]);
            w1p.x = pack2bf(v1[0], v1[1]);
            w1p.y = pack2bf(v1[2], v1[3]);
            *(uint2*)(bB + SWZ(p, cq * 64 + lg * 8)) = w0p;
            *(uint2*)(bB + SWZ(p, cq * 64 + 32 + lg * 8)) = w1p;
        }
        // ---- S4 (tile i-2): this wave's pixel half; acc-init = b_ol2
        if (i >= 2) {
            const char* bB = bufB[par];
            s8v bf[4];
            #pragma unroll
            for (int ks = 0; ks < 4; ++ks)
                bf[ks] = *(const s8v*)(bB + SWZ(p, ks * 64 + lg * 16));
            f4v acc = bias4;
            __builtin_amdgcn_s_setprio(1);
            #pragma unroll
            for (int ks = 0; ks < 4; ++ks)
                acc = __builtin_amdgcn_mfma_f32_16x16x32_bf16(w2f[ks], bf[ks], acc, 0, 0, 0);
            __builtin_amdgcn_s_setprio(0);
            #pragma unroll
            for (int r = 0; r < 4; ++r) {
                float xv = acc[r];
                float e = exp2f(-1.44269504f * fabsf(xv));
                spacc[r] += fmaf(0.69314718f, log2f(1.f + e), fmaxf(xv, 0.f));
            }
        }
        __syncthreads();
    }

    // reduce over the 16 pixel-lanes (l15); lanes l15==0 keep o = cq*16+lg*4+r
    #pragma unroll
    for (int m = 1; m <= 8; m <<= 1) {
        #pragma unroll
        for (int r = 0; r < 4; ++r) spacc[r] += __shfl_xor(spacc[r], m, 64);
    }
    if (l15 == 0) {
        #pragma unroll
        for (int r = 0; r < 4; ++r) red[w][lg * 4 + r] = spacc[r];
    }
    __syncthreads();
    if (t < 64) {
        int o = t, c = t >> 4;
        part[((size_t)b * NBX + bx) * 64 + o] = red[c][t & 15] + red[c + 4][t & 15];
    }
}

// ---------------------------------------------------------------------------
// K3: reduce partials + cls MLP (fp32), one block per image
// ---------------------------------------------------------------------------
__global__ __launch_bounds__(128) void k3_cls(
        const float* __restrict__ part,
        const float* __restrict__ w_cls1, const float* __restrict__ b_cls1,
        const float* __restrict__ w_cls2, const float* __restrict__ b_cls2,
        float* __restrict__ out) {
    __shared__ float es[64];
    __shared__ float hid[128];
    const int b = blockIdx.x, t = threadIdx.x;
    if (t < 64) {
        float s = 0.f;
        #pragma unroll
        for (int x = 0; x < NBX; ++x) s += part[((size_t)b * NBX + x) * 64 + t];
        es[t] = s;
    }
    __syncthreads();
    {
        float s = b_cls1[t];
        #pragma unroll
        for (int e = 0; e < 64; ++e) s = fmaf(es[e], w_cls1[e * 128 + t], s);
        hid[t] = fmaxf(s, 0.f);
    }
    __syncthreads();
    if (t < 10) {
        float s = b_cls2[t];
        #pragma unroll
        for (int h = 0; h < 128; ++h) s = fmaf(hid[h], w_cls2[h * 10 + t], s);
        out[b * 10 + t] = s;
    }
}

extern "C" void kernel_launch(void* const* d_in, const int* in_sizes, int n_in,
                              void* d_out, int out_size, void* d_ws, size_t ws_size,
                              hipStream_t stream) {
    (void)in_sizes; (void)n_in; (void)out_size; (void)ws_size;
    const float* images = (const float*)d_in[0];
    const float* w_obs1 = (const float*)d_in[1];
    const float* b_obs1 = (const float*)d_in[2];
    const float* w_obs2 = (const float*)d_in[3];
    const float* b_obs2 = (const float*)d_in[4];
    const float* w_loc1 = (const float*)d_in[5];
    const float* b_loc1 = (const float*)d_in[6];
    const float* w_loc2 = (const float*)d_in[7];
    const float* b_loc2 = (const float*)d_in[8];
    const float* w_ol1  = (const float*)d_in[9];
    const float* b_ol1  = (const float*)d_in[10];
    const float* w_ol2  = (const float*)d_in[11];
    const float* b_ol2  = (const float*)d_in[12];
    const float* w_cls1 = (const float*)d_in[13];
    const float* b_cls1 = (const float*)d_in[14];
    const float* w_cls2 = (const float*)d_in[15];
    const float* b_cls2 = (const float*)d_in[16];

    char* ws = (char*)d_ws;
    float* part           = (float*)(ws);                   // 32*24*64*4  = 196608
    float* biasc          = (float*)(ws + 196608);          // 512
    unsigned short* Wk    = (unsigned short*)(ws + 197120); // 49152
    unsigned short* wol2t = (unsigned short*)(ws + 246272); // 16384
    unsigned short* wloc2t= (unsigned short*)(ws + 262656); // 16384
    unsigned short* emloc = (unsigned short*)(ws + 279040); // 50176*64*2 = 6422528

    hipLaunchKernelGGL(k0_weights, dim3(161), dim3(256), 0, stream,
                       w_obs2, b_obs2, w_ol1, b_ol1, w_ol2, w_loc2, Wk, wol2t, wloc2t, biasc);
    hipLaunchKernelGGL(k1_loc, dim3(784), dim3(256), 0, stream,
                       w_loc1, b_loc1, wloc2t, b_loc2, emloc);
    hipLaunchKernelGGL(k2_main, dim3(NBX, 32), dim3(512), 0, stream,
                       images, w_obs1, b_obs1, Wk, biasc, wol2t, b_ol2, emloc, part);
    hipLaunchKernelGGL(k3_cls, dim3(32), dim3(128), 0, stream,
                       part, w_cls1, b_cls1, w_cls2, b_cls2, (float*)d_out);
}

// Round 17
// 183.697 us; speedup vs baseline: 1.2473x; 1.2473x over previous
//
#include <hip/hip_runtime.h>

#define N_PIX 50176
#define W_IMG 224
#define ROWS 32
#define NBX 24           // blocks per image: 3 blocks/CU; tiles contiguous

typedef __attribute__((ext_vector_type(8))) short s8v;   // 8 bf16
typedef __attribute__((ext_vector_type(4))) float f4v;
typedef __attribute__((ext_vector_type(2))) __bf16 bf2v;

__device__ __forceinline__ unsigned short f2bf(float f) {
    __bf16 h = (__bf16)f;
    return __builtin_bit_cast(unsigned short, h);
}
// pack two f32 -> two bf16 (RNE) in one u32; compiler emits v_cvt_pk_bf16_f32
__device__ __forceinline__ unsigned int pack2bf(float lo, float hi) {
    bf2v v = {(__bf16)lo, (__bf16)hi};
    return __builtin_bit_cast(unsigned int, v);
}

// swizzles: 256B rows (bufA/bufB), 128B rows (bufC/emloc)
#define SWZ(r, cb)  (((r) << 8) + ((cb) ^ (((r) & 15) << 4)))
#define CSWZ(r, cb) (((r) << 7) + ((cb) ^ (((r) & 7) << 4)))

__device__ __forceinline__ void gld_lds16(const void* g, void* l) {
    __builtin_amdgcn_global_load_lds(
        (const __attribute__((address_space(1))) unsigned int*)g,
        (__attribute__((address_space(3))) unsigned int*)l, 16, 0, 0);
}

// ---------------------------------------------------------------------------
// K0: Wk[col][k] (bf16, [128][192]): k<128 -> (w_obs2 @ w_ol1_top)^T
//                                    k>=128 -> w_ol1_bot^T  (em_loc extension)
//     wol2t[o][k]  = w_ol2^T  (bf16, [64][128])
//     wloc2t[o][k] = w_loc2^T (bf16, [64][128])
//     bias_c[h2]   = b_ol1[h2] + b_obs2 @ w_ol1_top
// ---------------------------------------------------------------------------
__global__ void k0_weights(const float* __restrict__ w_obs2, const float* __restrict__ b_obs2,
                           const float* __restrict__ w_ol1, const float* __restrict__ b_ol1,
                           const float* __restrict__ w_ol2, const float* __restrict__ w_loc2,
                           unsigned short* __restrict__ Wk,
                           unsigned short* __restrict__ wol2t,
                           unsigned short* __restrict__ wloc2t,
                           float* __restrict__ bias_c) {
    int bid = blockIdx.x, t = threadIdx.x;
    if (bid < 64) {
        int lin = bid * 256 + t;
        int n = lin >> 7, k = lin & 127;
        float s = 0.f;
        #pragma unroll
        for (int e = 0; e < 64; ++e) s = fmaf(w_obs2[k * 64 + e], w_ol1[e * 128 + n], s);
        Wk[n * 192 + k] = f2bf(s);
    } else if (bid < 96) {
        int lin = (bid - 64) * 256 + t;
        int n = lin >> 6, k = lin & 63;
        Wk[n * 192 + 128 + k] = f2bf(w_ol1[(64 + k) * 128 + n]);
    } else if (bid < 128) {
        int lin = (bid - 96) * 256 + t;
        int n = lin >> 7, k = lin & 127;
        wol2t[n * 128 + k] = f2bf(w_ol2[k * 64 + n]);
    } else if (bid < 160) {
        int lin = (bid - 128) * 256 + t;
        int n = lin >> 7, k = lin & 127;
        wloc2t[n * 128 + k] = f2bf(w_loc2[k * 64 + n]);
    } else {
        if (t < 128) {
            float s = b_ol1[t];
            #pragma unroll
            for (int e = 0; e < 64; ++e) s = fmaf(b_obs2[e], w_ol1[e * 128 + t], s);
            bias_c[t] = s;
        }
    }
}

// ---------------------------------------------------------------------------
// K1: em_loc via MFMA -> emloc stored PRE-SWIZZLED: element(n,o) at
//     emloc[n*64 + (o ^ ((n&7)<<3))]  (so k2 can DMA it linearly into LDS
//     and read with the CSWZ involution).
// ---------------------------------------------------------------------------
__global__ __launch_bounds__(256) void k1_loc(
        const float* __restrict__ w_loc1, const float* __restrict__ b_loc1,
        const unsigned short* __restrict__ wloc2t, const float* __restrict__ b_loc2,
        unsigned short* __restrict__ emloc) {
    __shared__ char hbuf[64 * 256];
    typedef __attribute__((ext_vector_type(4))) unsigned int u4v;

    const int t = threadIdx.x;
    const int n0 = blockIdx.x * 64;
    const int row = t >> 2, h0 = (t & 3) * 32;
    {
        int n = n0 + row;
        int iy = n / W_IMG, ix = n % W_IMG;
        float y = -10.f + (20.f / 223.f) * (float)iy;
        float x = -10.f + (20.f / 223.f) * (float)ix;
        #pragma unroll
        for (int q4 = 0; q4 < 4; ++q4) {
            int hb = h0 + q4 * 8;
            u4v pk;
            #pragma unroll
            for (int jj = 0; jj < 2; ++jj) {
                f4v wy = *(const f4v*)(w_loc1 + hb + jj * 4);
                f4v wx = *(const f4v*)(w_loc1 + 128 + hb + jj * 4);
                f4v bb = *(const f4v*)(b_loc1 + hb + jj * 4);
                #pragma unroll
                for (int j2 = 0; j2 < 2; ++j2) {
                    float v0 = fmaxf(fmaf(y, wy[j2 * 2], fmaf(x, wx[j2 * 2], bb[j2 * 2])), 0.f);
                    float v1 = fmaxf(fmaf(y, wy[j2 * 2 + 1], fmaf(x, wx[j2 * 2 + 1], bb[j2 * 2 + 1])), 0.f);
                    pk[jj * 2 + j2] = pack2bf(v0, v1);
                }
            }
            *(u4v*)(hbuf + SWZ(row, hb * 2)) = pk;
        }
    }
    __syncthreads();
    {
        const int w = t >> 6, l = t & 63;
        const int l15 = l & 15, lg = l >> 4;
        s8v a[4];
        #pragma unroll
        for (int ks = 0; ks < 4; ++ks)
            a[ks] = *(const s8v*)(hbuf + SWZ(w * 16 + l15, ks * 64 + lg * 16));
        #pragma unroll
        for (int nt = 0; nt < 4; ++nt) {
            f4v acc = {0.f, 0.f, 0.f, 0.f};
            #pragma unroll
            for (int ks = 0; ks < 4; ++ks) {
                s8v bfr = *(const s8v*)(wloc2t + (nt * 16 + l15) * 128 + ks * 32 + lg * 8);
                acc = __builtin_amdgcn_mfma_f32_16x16x32_bf16(a[ks], bfr, acc, 0, 0, 0);
            }
            float bb = b_loc2[nt * 16 + l15];
            int o = nt * 16 + l15;
            #pragma unroll
            for (int r = 0; r < 4; ++r) {
                int n = n0 + w * 16 + lg * 4 + r;
                emloc[(size_t)n * 64 + (o ^ ((n & 7) << 3))] = f2bf(acc[r] + bb);
            }
        }
    }
}

// ---------------------------------------------------------------------------
// K2: 3-stage pipeline, 1 barrier/iter, DMA-prefetched inputs.
//   Grid 24 x 32 = 768 blocks = 3 blocks/CU. (256,2) reg cap — never tighten.
//   PLATEAU CONFIG (R15): 4-wave blocks, 16x16x32 MFMAs, two independent S3
//   acc chains, bias carried in MFMA C-in, exp2/log2 softplus. All occupancy
//   levers benched worse: LDS-exact-fit 4th block (R11), reg-prefetch (R12),
//   32x32 MFMA (R14), 8-wave split (R16).
// ---------------------------------------------------------------------------
__global__ __launch_bounds__(256, 2) void k2_main(
        const float* __restrict__ images,
        const float* __restrict__ w_obs1, const float* __restrict__ b_obs1,
        const unsigned short* __restrict__ Wk, const float* __restrict__ biasc,
        const unsigned short* __restrict__ wol2t, const float* __restrict__ b_ol2,
        const unsigned short* __restrict__ emloc,
        float* __restrict__ part)          // [32][24][64]
{
    __shared__ char bufA[2][ROWS * 256];
    __shared__ char bufB[2][ROWS * 256];
    __shared__ char bufC[2][ROWS * 128];
    __shared__ f4v bufI4[2][24];           // [ch][32] floats per buffer
    __shared__ float red[4][16];

    const int t = threadIdx.x;
    const int w = t >> 6, l = t & 63;
    const int l15 = l & 15, lg = l >> 4;
    const int cq = w;
    const int bx = blockIdx.x, b = blockIdx.y;
    const int start = bx * 65 + (bx < 8 ? bx : 8);
    const int cnt = 65 + (bx < 8 ? 1 : 0);
    const size_t imgb = (size_t)b * 3 * N_PIX;
    #define PBASE(k) ((start + (k)) * ROWS)

    // S1 A-fragments (persistent): [w_obs1 | b_obs1] for 2 h-tiles of 16.
    // k-slots 0..3 = {w[0][h], w[1][h], w[2][h], b[h]}; lanes lg>=1 hold ZERO.
    s8v a1[2];
    #pragma unroll
    for (int mt = 0; mt < 2; ++mt) {
        int hh = cq * 32 + mt * 16 + l15;
        unsigned int lo = pack2bf(w_obs1[hh], w_obs1[128 + hh]);
        unsigned int hi = pack2bf(w_obs1[256 + hh], b_obs1[hh]);
        if (lg != 0) { lo = 0u; hi = 0u; }
        typedef __attribute__((ext_vector_type(4))) unsigned int u4;
        u4 u = {lo, hi, 0u, 0u};
        a1[mt] = __builtin_bit_cast(s8v, u);
    }

    // GEMM1 A fragments (weights, persistent): 2 h2-tiles x 6 k-steps
    s8v bw[2][6];
    #pragma unroll
    for (int nt = 0; nt < 2; ++nt) {
        int col = cq * 32 + nt * 16 + l15;
        #pragma unroll
        for (int ks = 0; ks < 6; ++ks)
            bw[nt][ks] = *(const s8v*)(Wk + col * 192 + ks * 32 + lg * 8);
    }
    // GEMM2 A fragments
    s8v w2f[4];
    {
        int o = cq * 16 + l15;
        #pragma unroll
        for (int ks = 0; ks < 4; ++ks)
            w2f[ks] = *(const s8v*)(wol2t + o * 128 + ks * 32 + lg * 8);
    }
    // bias vectors double as MFMA C-in (D row depends only on lg,r = the
    // f4v lane indexing; col-invariant, so acc-init is exact)
    const f4v bias30 = *(const f4v*)(biasc + cq * 32 + lg * 4);
    const f4v bias31 = *(const f4v*)(biasc + cq * 32 + 16 + lg * 4);
    const f4v bias4  = *(const f4v*)(b_ol2 + cq * 16 + lg * 4);

    f4v spacc = {0.f, 0.f, 0.f, 0.f};

    // preload img tile 0 (wave 1, 24 lanes x 16B = 3 ch x 128B)
    if (w == 1 && l < 24) {
        const char* src = (const char*)(images + imgb + (l >> 3) * N_PIX + PBASE(0)) + (l & 7) * 16;
        gld_lds16(src, (char*)bufI4[0]);
    }
    __syncthreads();

    for (int i = 0; i <= cnt + 1; ++i) {
        const int par = i & 1;
        // ---- DMA: emloc tile i -> bufC[par] (all 256 threads, 16B each)
        if (i < cnt) {
            const char* src = (const char*)emloc +
                (size_t)(PBASE(i) + w * 8 + (l >> 3)) * 128 + (l & 7) * 16;
            gld_lds16(src, (char*)bufC[par] + w * 1024);
        }
        // ---- DMA: img tile i+1 -> bufI[par^1] (wave 1, 24 lanes)
        if (i + 1 < cnt && w == 1 && l < 24) {
            const char* src = (const char*)(images + imgb + (l >> 3) * N_PIX +
                                            PBASE(i + 1)) + (l & 7) * 16;
            gld_lds16(src, (char*)bufI4[par ^ 1]);
        }
        // ---- S1 (MFMA): hidden_obs(tile i) -> bufA[par]
        if (i < cnt) {
            const float* bI = (const float*)bufI4[par];
            char* bA = bufA[par];
            #pragma unroll
            for (int nt2 = 0; nt2 < 2; ++nt2) {
                const int p = nt2 * 16 + l15;
                float x0 = bI[p], x1 = bI[32 + p], x2 = bI[64 + p];
                typedef __attribute__((ext_vector_type(4))) unsigned int u4;
                u4 u = {pack2bf(x0, x1), pack2bf(x2, 1.0f), 0u, 0u};
                s8v bfr = __builtin_bit_cast(s8v, u);
                #pragma unroll
                for (int mt = 0; mt < 2; ++mt) {
                    f4v acc = {0.f, 0.f, 0.f, 0.f};
                    acc = __builtin_amdgcn_mfma_f32_16x16x32_bf16(a1[mt], bfr, acc, 0, 0, 0);
                    f4v z = {0.f, 0.f, 0.f, 0.f};
                    acc = __builtin_elementwise_max(acc, z);
                    uint2 pk;
                    pk.x = pack2bf(acc[0], acc[1]);
                    pk.y = pack2bf(acc[2], acc[3]);
                    // h = cq*32 + mt*16 + lg*4 + r, pixel = p
                    *(uint2*)(bA + SWZ(p, cq * 64 + mt * 32 + lg * 8)) = pk;
                }
            }
        }
        // ---- S3 (tile i-1): B = activations from bufA/bufC, A = bw regs;
        //      acc chains INITIALIZED with bias30/bias31
        if (i >= 1 && i <= cnt) {
            const char* bA = bufA[par ^ 1];
            const char* bC = bufC[par ^ 1];
            char* bB = bufB[par ^ 1];
            #pragma unroll
            for (int ms = 0; ms < 2; ++ms) {
                const int p = ms * 16 + l15;
                s8v bf[4];
                #pragma unroll
                for (int ks = 0; ks < 4; ++ks)
                    bf[ks] = *(const s8v*)(bA + SWZ(p, ks * 64 + lg * 16));
                s8v c0 = *(const s8v*)(bC + CSWZ(p, lg * 16));
                s8v c1 = *(const s8v*)(bC + CSWZ(p, lg * 16 + 64));
                f4v acc0 = bias30, acc1 = bias31;
                __builtin_amdgcn_s_setprio(1);
                #pragma unroll
                for (int ks = 0; ks < 4; ++ks) {
                    acc0 = __builtin_amdgcn_mfma_f32_16x16x32_bf16(bw[0][ks], bf[ks], acc0, 0, 0, 0);
                    acc1 = __builtin_amdgcn_mfma_f32_16x16x32_bf16(bw[1][ks], bf[ks], acc1, 0, 0, 0);
                }
                acc0 = __builtin_amdgcn_mfma_f32_16x16x32_bf16(bw[0][4], c0, acc0, 0, 0, 0);
                acc1 = __builtin_amdgcn_mfma_f32_16x16x32_bf16(bw[1][4], c0, acc1, 0, 0, 0);
                acc0 = __builtin_amdgcn_mfma_f32_16x16x32_bf16(bw[0][5], c1, acc0, 0, 0, 0);
                acc1 = __builtin_amdgcn_mfma_f32_16x16x32_bf16(bw[1][5], c1, acc1, 0, 0, 0);
                __builtin_amdgcn_s_setprio(0);
                // D[h2][pixel=p] -> bufB[p][h2], 4 consecutive h2 per acc
                f4v z = {0.f, 0.f, 0.f, 0.f};
                f4v v0 = __builtin_elementwise_max(acc0, z);
                f4v v1 = __builtin_elementwise_max(acc1, z);
                uint2 w0p, w1p;
                w0p.x = pack2bf(v0[0], v0[1]);
                w0p.y = pack2bf(v0[2], v0[3]);
                w1p.x = pack2bf(v1[0], v1[1]);
                w1p.y = pack2bf(v1[2], v1[3]);
                *(uint2*)(bB + SWZ(p, cq * 64 + lg * 8)) = w0p;
                *(uint2*)(bB + SWZ(p, cq * 64 + 32 + lg * 8)) = w1p;
            }
        }
        // ---- S4 (tile i-2): B = bufB, A = w2f regs; acc-init = b_ol2;
        //      softplus = fma(ln2, log2(1+exp2(-log2e*|x|)), max(x,0))
        if (i >= 2) {
            const char* bB = bufB[par];
            #pragma unroll
            for (int ms = 0; ms < 2; ++ms) {
                const int p = ms * 16 + l15;
                s8v bf[4];
                #pragma unroll
                for (int ks = 0; ks < 4; ++ks)
                    bf[ks] = *(const s8v*)(bB + SWZ(p, ks * 64 + lg * 16));
                f4v acc = bias4;
                __builtin_amdgcn_s_setprio(1);
                #pragma unroll
                for (int ks = 0; ks < 4; ++ks)
                    acc = __builtin_amdgcn_mfma_f32_16x16x32_bf16(w2f[ks], bf[ks], acc, 0, 0, 0);
                __builtin_amdgcn_s_setprio(0);
                #pragma unroll
                for (int r = 0; r < 4; ++r) {
                    float xv = acc[r];
                    float e = exp2f(-1.44269504f * fabsf(xv));
                    spacc[r] += fmaf(0.69314718f, log2f(1.f + e), fmaxf(xv, 0.f));
                }
            }
        }
        __syncthreads();
    }

    // reduce over the 16 pixel-lanes (l15); lanes l15==0 keep o = cq*16+lg*4+r
    #pragma unroll
    for (int m = 1; m <= 8; m <<= 1) {
        #pragma unroll
        for (int r = 0; r < 4; ++r) spacc[r] += __shfl_xor(spacc[r], m, 64);
    }
    if (l15 == 0) {
        #pragma unroll
        for (int r = 0; r < 4; ++r) red[w][lg * 4 + r] = spacc[r];
    }
    __syncthreads();
    if (t < 64) part[((size_t)b * NBX + bx) * 64 + t] = red[t >> 4][t & 15];
}

// ---------------------------------------------------------------------------
// K3: reduce partials + cls MLP (fp32), one block per image
// ---------------------------------------------------------------------------
__global__ __launch_bounds__(128) void k3_cls(
        const float* __restrict__ part,
        const float* __restrict__ w_cls1, const float* __restrict__ b_cls1,
        const float* __restrict__ w_cls2, const float* __restrict__ b_cls2,
        float* __restrict__ out) {
    __shared__ float es[64];
    __shared__ float hid[128];
    const int b = blockIdx.x, t = threadIdx.x;
    if (t < 64) {
        float s = 0.f;
        #pragma unroll
        for (int x = 0; x < NBX; ++x) s += part[((size_t)b * NBX + x) * 64 + t];
        es[t] = s;
    }
    __syncthreads();
    {
        float s = b_cls1[t];
        #pragma unroll
        for (int e = 0; e < 64; ++e) s = fmaf(es[e], w_cls1[e * 128 + t], s);
        hid[t] = fmaxf(s, 0.f);
    }
    __syncthreads();
    if (t < 10) {
        float s = b_cls2[t];
        #pragma unroll
        for (int h = 0; h < 128; ++h) s = fmaf(hid[h], w_cls2[h * 10 + t], s);
        out[b * 10 + t] = s;
    }
}

extern "C" void kernel_launch(void* const* d_in, const int* in_sizes, int n_in,
                              void* d_out, int out_size, void* d_ws, size_t ws_size,
                              hipStream_t stream) {
    (void)in_sizes; (void)n_in; (void)out_size; (void)ws_size;
    const float* images = (const float*)d_in[0];
    const float* w_obs1 = (const float*)d_in[1];
    const float* b_obs1 = (const float*)d_in[2];
    const float* w_obs2 = (const float*)d_in[3];
    const float* b_obs2 = (const float*)d_in[4];
    const float* w_loc1 = (const float*)d_in[5];
    const float* b_loc1 = (const float*)d_in[6];
    const float* w_loc2 = (const float*)d_in[7];
    const float* b_loc2 = (const float*)d_in[8];
    const float* w_ol1  = (const float*)d_in[9];
    const float* b_ol1  = (const float*)d_in[10];
    const float* w_ol2  = (const float*)d_in[11];
    const float* b_ol2  = (const float*)d_in[12];
    const float* w_cls1 = (const float*)d_in[13];
    const float* b_cls1 = (const float*)d_in[14];
    const float* w_cls2 = (const float*)d_in[15];
    const float* b_cls2 = (const float*)d_in[16];

    char* ws = (char*)d_ws;
    float* part           = (float*)(ws);                   // 32*24*64*4  = 196608
    float* biasc          = (float*)(ws + 196608);          // 512
    unsigned short* Wk    = (unsigned short*)(ws + 197120); // 49152
    unsigned short* wol2t = (unsigned short*)(ws + 246272); // 16384
    unsigned short* wloc2t= (unsigned short*)(ws + 262656); // 16384
    unsigned short* emloc = (unsigned short*)(ws + 279040); // 50176*64*2 = 6422528

    hipLaunchKernelGGL(k0_weights, dim3(161), dim3(256), 0, stream,
                       w_obs2, b_obs2, w_ol1, b_ol1, w_ol2, w_loc2, Wk, wol2t, wloc2t, biasc);
    hipLaunchKernelGGL(k1_loc, dim3(784), dim3(256), 0, stream,
                       w_loc1, b_loc1, wloc2t, b_loc2, emloc);
    hipLaunchKernelGGL(k2_main, dim3(NBX, 32), dim3(256), 0, stream,
                       images, w_obs1, b_obs1, Wk, biasc, wol2t, b_ol2, emloc, part);
    hipLaunchKernelGGL(k3_cls, dim3(32), dim3(128), 0, stream,
                       part, w_cls1, b_cls1, w_cls2, b_cls2, (float*)d_out);
}